// Round 5
// baseline (433.563 us; speedup 1.0000x reference)
//
#include <hip/hip_runtime.h>

#define N_NODES 8192
#define CAP 128    // neighbor capacity; Binomial(8192,1/256): P(deg>128) ~ 0
constexpr int AST = 132;  // activation LDS row stride (floats), 16B-aligned

typedef unsigned u32x4 __attribute__((ext_vector_type(4)));
typedef unsigned short u16;
typedef __attribute__((ext_vector_type(8))) short bf16x8;
typedef __attribute__((ext_vector_type(4))) float f32x4;

// Pre-split DECODER weight fragment regions (u16 elements): K*F each.
constexpr size_t OFF_WD  = 0;        // 128*128 = 16384
constexpr size_t OFF_WP1 = 16384;    // 256*128 = 32768
constexpr size_t OFF_WP2 = 49152;    // 128*64  = 8192
constexpr size_t OFF_WO  = 57344;    // 64*16   = 1024 (cols 8..15 zero-pad)
constexpr size_t WTOT    = 58368;    // = 228 * 256 exactly

// Fused kernel block-role layout.
#define ENC_BLOCKS 128               // 4 waves x 16 nodes = 64 nodes/block
#define SCAN_BLOCKS 2048             // 4 rows/block (1 per wave)
#define PREP_BLOCKS 228              // WTOT/256
#define FUSED_GRID (ENC_BLOCKS + SCAN_BLOCKS + PREP_BLOCKS)

// ---------------------------------------------------------------------------
// MFMA split-bf16 layer: one wave computes a 16-node x F output tile.
// A fragment: lane holds act[row = lane&15][k = ks*32 + (lane>>4)*8 + j].
// C/D mapping (HW-verified): col = lane&15, row = (lane>>4)*4 + r.
// D += Ahi*Bhi + Ahi*Blo + Alo*Bhi  (lo*lo ~ 2^-16 rel, dropped).
// RAWB: split B on the fly from row-major f32 W[F][K] (no prep needed).
// SCALEMODE: 0 none, 1 mask[node] (with F==16: only f<8 stored).
// ---------------------------------------------------------------------------
template <int K, int F, int KSPLIT, int SA, int SO, bool RELU, bool BIAS,
          int SCALEMODE, bool RAWB>
__device__ __forceinline__ void mfma_layer(
    const float (*__restrict__ A0)[SA], const float (*__restrict__ A1)[SA],
    const u16* __restrict__ Bh, const u16* __restrict__ Bl,
    const float* __restrict__ Wraw,
    const float* __restrict__ bias, float (*__restrict__ O)[SO],
    float* __restrict__ gout, int gstride,
    const float* __restrict__ mask, int nbase, int lane) {
  constexpr int NK = K / 32, NF = F / 16;
  f32x4 acc[NF];
  const f32x4 zz = {0.f, 0.f, 0.f, 0.f};
#pragma unroll
  for (int i = 0; i < NF; ++i) acc[i] = zz;
  const int arow = lane & 15;
  const int kgrp = (lane >> 4) << 3;
#pragma unroll
  for (int ks = 0; ks < NK; ++ks) {
    const float* ap = (ks * 32 < KSPLIT) ? &A0[arow][ks * 32 + kgrp]
                                         : &A1[arow][ks * 32 - KSPLIT + kgrp];
    const float4 p0 = *(const float4*)ap;
    const float4 p1 = *(const float4*)(ap + 4);
    const float av[8] = {p0.x, p0.y, p0.z, p0.w, p1.x, p1.y, p1.z, p1.w};
    bf16x8 ahi, alo;
#pragma unroll
    for (int j = 0; j < 8; ++j) {
      const unsigned u = __float_as_uint(av[j]);
      const unsigned uh = u & 0xffff0000u;
      const float r = av[j] - __uint_as_float(uh);
      ahi[j] = (short)(uh >> 16);
      alo[j] = (short)(__float_as_uint(r) >> 16);
    }
#pragma unroll
    for (int ft = 0; ft < NF; ++ft) {
      bf16x8 wh, wl;
      if (RAWB) {
        const float* wp = Wraw + (size_t)(ft * 16 + arow) * K + ks * 32 + kgrp;
        const float4 q0 = *(const float4*)wp;
        const float4 q1 = *(const float4*)(wp + 4);
        const float wv[8] = {q0.x, q0.y, q0.z, q0.w, q1.x, q1.y, q1.z, q1.w};
#pragma unroll
        for (int j = 0; j < 8; ++j) {
          const unsigned u = __float_as_uint(wv[j]);
          const unsigned uh = u & 0xffff0000u;
          const float r = wv[j] - __uint_as_float(uh);
          wh[j] = (short)(uh >> 16);
          wl[j] = (short)(__float_as_uint(r) >> 16);
        }
      } else {
        const size_t idx = ((size_t)(ks * NF + ft) * 64 + lane) * 8;
        wh = *(const bf16x8*)(Bh + idx);
        wl = *(const bf16x8*)(Bl + idx);
      }
      acc[ft] = __builtin_amdgcn_mfma_f32_16x16x32_bf16(ahi, wh, acc[ft], 0, 0, 0);
      acc[ft] = __builtin_amdgcn_mfma_f32_16x16x32_bf16(ahi, wl, acc[ft], 0, 0, 0);
      acc[ft] = __builtin_amdgcn_mfma_f32_16x16x32_bf16(alo, wh, acc[ft], 0, 0, 0);
    }
  }
#pragma unroll
  for (int ft = 0; ft < NF; ++ft) {
    const int f = ft * 16 + (lane & 15);
    if (SCALEMODE == 1 && F == 16 && f >= 8) continue;  // zero-padded cols
    const float bv = BIAS ? bias[f] : 0.f;
#pragma unroll
    for (int r = 0; r < 4; ++r) {
      const int row = ((lane >> 4) << 2) + r;
      const int node = nbase + row;
      float v = acc[ft][r];
      if (BIAS) v += bv;
      if (RELU) v = fmaxf(v, 0.f);
      if (SCALEMODE == 1) v *= mask[node];
      if (O) O[row][f] = v;
      if (gout) gout[(size_t)node * gstride + f] = v;
    }
  }
}

// ---------------------------------------------------------------------------
// Fused kernel: three disjoint block roles, all independent.
//   [0, ENC)             : encoder, 4 waves x 16 nodes. x -> h1 -> h(global);
//                          msg_raw = h @ wg.T (UNSCALED; dinv applied in agg).
//                          B-fragments split on the fly from raw f32 weights.
//   [ENC, ENC+SCAN)      : adj scan -> cnt/dinv/nbr. Proven R0 structure,
//                          byte-identical inner loop, nontemporal loads.
//   [ENC+SCAN, ..+PREP)  : pre-split decoder weights into bh/bl (consumed
//                          two launches later by mfma_decode).
// Encoder blocks come first so they start while scan saturates HBM.
// ---------------------------------------------------------------------------
__global__ __launch_bounds__(256, 2) void fused_sep_kernel(
    const float* __restrict__ adj, const float* __restrict__ x,
    const float* __restrict__ w1, const float* __restrict__ b1,
    const float* __restrict__ w2, const float* __restrict__ b2,
    const float* __restrict__ wg,
    const float* __restrict__ wd, const float* __restrict__ wp1,
    const float* __restrict__ wp2, const float* __restrict__ wo,
    int* __restrict__ cnt, float* __restrict__ dinv, int* __restrict__ nbr,
    float* __restrict__ h_out, float* __restrict__ msg_out,
    u16* __restrict__ bh, u16* __restrict__ bl) {
  __shared__ float actX[4][16][36];
  __shared__ float actH1[4][16][68];
  __shared__ float actH[4][16][AST];
  const int t = threadIdx.x;
  const int bid = blockIdx.x;

  if (bid < ENC_BLOCKS) {
    // ---- encoder path: 4 waves, each owns a 16-node tile.
    const int w = t >> 6, lane = t & 63;
    const int n0 = bid * 64 + w * 16;
#pragma unroll
    for (int i = 0; i < 2; ++i) {  // stage x: 64 rows x 8 float4 = 512 float4
      const int fi = i * 256 + t;
      const int row = fi >> 3, c4 = (fi & 7) * 4;
      *(float4*)&actX[0][0][(size_t)row * 36 + c4] =
          *(const float4*)&x[(size_t)(bid * 64 + row) * 32 + c4];
    }
    __syncthreads();
    mfma_layer<32, 64, 32, 36, 68, true, true, 0, true>(
        actX[w], actX[w], nullptr, nullptr, w1, b1, actH1[w],
        nullptr, 0, nullptr, n0, lane);
    __syncthreads();
    mfma_layer<64, 128, 64, 68, AST, true, true, 0, true>(
        actH1[w], actH1[w], nullptr, nullptr, w2, b2, actH[w],
        h_out, 128, nullptr, n0, lane);
    __syncthreads();
    mfma_layer<128, 128, 128, AST, AST, false, false, 0, true>(
        actH[w], actH[w], nullptr, nullptr, wg, nullptr, (float(*)[AST])nullptr,
        msg_out, 128, nullptr, n0, lane);
  } else if (bid < ENC_BLOCKS + SCAN_BLOCKS) {
    // ---- scan path: one row per wave, zero barriers, chunk double-buffer.
    const int lane = t & 63;
    const int row = (bid - ENC_BLOCKS) * 4 + (t >> 6);
    const u32x4* rowp = (const u32x4*)(adj + (size_t)row * N_NODES);
    u32x4 v[8], vn[8];
#pragma unroll
    for (int i = 0; i < 8; ++i) v[i] = __builtin_nontemporal_load(&rowp[i * 64 + lane]);
    int running = 0;
    int* nbr_row = nbr + (size_t)row * CAP;
    for (int ch = 0; ch < 4; ++ch) {
      if (ch < 3) {  // prefetch next chunk while consuming current
        const u32x4* cp = rowp + (ch + 1) * 512;
#pragma unroll
        for (int i = 0; i < 8; ++i) vn[i] = __builtin_nontemporal_load(&cp[i * 64 + lane]);
      }
      int c = 0;
#pragma unroll
      for (int i = 0; i < 8; ++i)
        c += (v[i].x != 0u) + (v[i].y != 0u) + (v[i].z != 0u) + (v[i].w != 0u);
      int incl = c;  // wave-inclusive prefix scan, shuffles only
#pragma unroll
      for (int s = 1; s < 64; s <<= 1) {
        int n = __shfl_up(incl, s);
        if (lane >= s) incl += n;
      }
      int off = running + incl - c;
      running += __shfl(incl, 63);
      const int colbase = ch * 2048;
#pragma unroll
      for (int i = 0; i < 8; ++i) {
        if (v[i].x | v[i].y | v[i].z | v[i].w) {
          const int col = colbase + (i * 64 + lane) * 4;
          if (v[i].x) { if (off < CAP) nbr_row[off] = col + 0; ++off; }
          if (v[i].y) { if (off < CAP) nbr_row[off] = col + 1; ++off; }
          if (v[i].z) { if (off < CAP) nbr_row[off] = col + 2; ++off; }
          if (v[i].w) { if (off < CAP) nbr_row[off] = col + 3; ++off; }
        }
      }
#pragma unroll
      for (int i = 0; i < 8; ++i) v[i] = vn[i];
    }
    if (lane == 0) {
      cnt[row] = running;
      dinv[row] = rsqrtf((float)running + 1.0f);
    }
  } else {
    // ---- prep path: split decoder weights into fragment-major bf16 pairs.
    const int gid = (bid - ENC_BLOCKS - SCAN_BLOCKS) * 256 + t;
    if (gid >= (int)WTOT) return;
    const float* W; int K, F; size_t off; int rel; bool pad = false;
    if (gid < 16384)      { W = wd;  K = 128; F = 128; off = OFF_WD;  rel = gid; }
    else if (gid < 49152) { W = wp1; K = 256; F = 128; off = OFF_WP1; rel = gid - 16384; }
    else if (gid < 57344) { W = wp2; K = 128; F = 64;  off = OFF_WP2; rel = gid - 49152; }
    else                  { W = wo;  K = 64;  F = 16;  off = OFF_WO;  rel = gid - 57344; pad = true; }
    const int j = rel & 7, lane8 = (rel >> 3) & 63, t2 = rel >> 9;
    const int nf = F >> 4;
    const int ftile = t2 % nf, kstep = t2 / nf;
    const int k = kstep * 32 + ((lane8 >> 4) << 3) + j;
    const int f = ftile * 16 + (lane8 & 15);
    const float v = (pad && f >= 8) ? 0.f : W[(size_t)f * K + k];
    const unsigned u = __float_as_uint(v);
    const unsigned uh = u & 0xffff0000u;
    const float r = v - __uint_as_float(uh);
    bh[off + rel] = (u16)(uh >> 16);
    bl[off + rel] = (u16)(__float_as_uint(r) >> 16);
  }
}

// ---------------------------------------------------------------------------
// Kernel 2: agg. msg is UNSCALED; dinv applied per-gather via fmaf (numerics
// verified in R1). g1 = relu(dinv_r * (dinv_r*msg_r + sum dinv_j*msg_j) + bg).
// ---------------------------------------------------------------------------
__global__ __launch_bounds__(256) void agg_kernel(
    const int* __restrict__ cnt, const float* __restrict__ dinv,
    const int* __restrict__ nbr, const float* __restrict__ msg,
    const float* __restrict__ bg, const float* __restrict__ adj,
    float* __restrict__ g1) {
  const int t = threadIdx.x;
  const int f = t & 127;
  const int rA = blockIdx.x * 4 + (t >> 7) * 2;
  const int rB = rA + 1;
  const int cA = cnt[rA], cB = cnt[rB];
  const float dvA = dinv[rA], dvB = dinv[rB];
  float a0 = dvA * msg[(size_t)rA * 128 + f];  // self-loop term
  float a1 = dvB * msg[(size_t)rB * 128 + f];
  if (cA <= CAP && cB <= CAP) {
    const int* nA = nbr + (size_t)rA * CAP;
    const int* nB = nbr + (size_t)rB * CAP;
    const int cm = max(cA, cB);
    for (int i = 0; i < cm; i += 4) {
#pragma unroll
      for (int k = 0; k < 4; ++k) {
        const int ii = i + k;
        int jA = nA[ii < cA ? ii : 0] & (N_NODES - 1);
        int jB = nB[ii < cB ? ii : 0] & (N_NODES - 1);
        const float wA = (ii < cA) ? dinv[jA] : 0.f;
        const float wB = (ii < cB) ? dinv[jB] : 0.f;
        a0 = fmaf(wA, msg[(size_t)jA * 128 + f], a0);
        a1 = fmaf(wB, msg[(size_t)jB * 128 + f], a1);
      }
    }
  } else {  // statistically unreachable dense fallback
    for (int col = 0; col < N_NODES; ++col) {
      if (adj[(size_t)rA * N_NODES + col] != 0.f)
        a0 = fmaf(dinv[col], msg[(size_t)col * 128 + f], a0);
      if (adj[(size_t)rB * N_NODES + col] != 0.f)
        a1 = fmaf(dinv[col], msg[(size_t)col * 128 + f], a1);
    }
  }
  g1[(size_t)rA * 128 + f] = fmaxf(fmaf(dvA, a0, bg[f]), 0.f);
  g1[(size_t)rB * 128 + f] = fmaxf(fmaf(dvB, a1, bg[f]), 0.f);
}

// ---------------------------------------------------------------------------
// Kernel 3: MFMA decoder (R3/R4, proven). 2 waves x 16 nodes, wave-private
// LDS. g1 -> g2 -> p1([g2|h]) -> p2 -> out * mask.
// ---------------------------------------------------------------------------
__global__ __launch_bounds__(128) void mfma_decode(
    const float* __restrict__ g1, const float* __restrict__ h,
    const u16* __restrict__ bh, const u16* __restrict__ bl,
    const float* __restrict__ bd, const float* __restrict__ bp1,
    const float* __restrict__ bp2, const float* __restrict__ bo,
    const float* __restrict__ mask, float* __restrict__ out) {
  __shared__ float actA[2][16][AST];
  __shared__ float actB[2][16][AST];
  __shared__ float actH[2][16][AST];
  const int t = threadIdx.x;
  const int w = t >> 6, lane = t & 63;
  const int n0 = blockIdx.x * 32 + w * 16;
#pragma unroll
  for (int i = 0; i < 8; ++i) {  // stage g1 + h: 16 rows x 32 float4 each
    const int fi = i * 64 + lane;
    const int row = fi >> 5, c4 = (fi & 31) * 4;
    *(float4*)&actA[w][row][c4] = *(const float4*)&g1[(size_t)(n0 + row) * 128 + c4];
    *(float4*)&actH[w][row][c4] = *(const float4*)&h[(size_t)(n0 + row) * 128 + c4];
  }
  __syncthreads();
  mfma_layer<128, 128, 128, AST, AST, true, true, 0, false>(
      actA[w], actA[w], bh + OFF_WD, bl + OFF_WD, nullptr, bd, actB[w],
      nullptr, 0, nullptr, n0, lane);
  __syncthreads();
  mfma_layer<256, 128, 128, AST, AST, true, true, 0, false>(
      actB[w], actH[w], bh + OFF_WP1, bl + OFF_WP1, nullptr, bp1, actA[w],
      nullptr, 0, nullptr, n0, lane);
  __syncthreads();
  mfma_layer<128, 64, 128, AST, AST, true, true, 0, false>(
      actA[w], actA[w], bh + OFF_WP2, bl + OFF_WP2, nullptr, bp2, actB[w],
      nullptr, 0, nullptr, n0, lane);
  __syncthreads();
  mfma_layer<64, 16, 128, AST, AST, false, true, 1, false>(
      actB[w], actB[w], bh + OFF_WO, bl + OFF_WO, nullptr, bo,
      (float(*)[AST])nullptr, out, 8, mask, n0, lane);
}

extern "C" void kernel_launch(void* const* d_in, const int* in_sizes, int n_in,
                              void* d_out, int out_size, void* d_ws, size_t ws_size,
                              hipStream_t stream) {
  const float* x    = (const float*)d_in[0];
  const float* adj  = (const float*)d_in[1];
  const float* mask = (const float*)d_in[2];
  const float* w1   = (const float*)d_in[3];
  const float* b1   = (const float*)d_in[4];
  const float* w2   = (const float*)d_in[5];
  const float* b2   = (const float*)d_in[6];
  const float* wg   = (const float*)d_in[7];
  const float* bg   = (const float*)d_in[8];
  const float* wd   = (const float*)d_in[9];
  const float* bd   = (const float*)d_in[10];
  const float* wp1  = (const float*)d_in[11];
  const float* bp1  = (const float*)d_in[12];
  const float* wp2  = (const float*)d_in[13];
  const float* bp2  = (const float*)d_in[14];
  const float* wo   = (const float*)d_in[15];
  const float* bo   = (const float*)d_in[16];
  float* out = (float*)d_out;

  float* ws = (float*)d_ws;
  float* h    = ws; ws += (size_t)N_NODES * 128;
  float* msg  = ws; ws += (size_t)N_NODES * 128;
  float* g1   = ws; ws += (size_t)N_NODES * 128;
  float* dinv = ws; ws += N_NODES;
  int* cnt = (int*)ws; ws += N_NODES;
  int* nbr = (int*)ws; ws += (size_t)N_NODES * CAP;
  u16* bh = (u16*)ws;
  u16* bl = bh + WTOT;

  fused_sep_kernel<<<FUSED_GRID, 256, 0, stream>>>(
      adj, x, w1, b1, w2, b2, wg, wd, wp1, wp2, wo,
      cnt, dinv, nbr, h, msg, bh, bl);
  agg_kernel<<<N_NODES / 4, 256, 0, stream>>>(cnt, dinv, nbr, msg, bg, adj, g1);
  mfma_decode<<<N_NODES / 32, 128, 0, stream>>>(
      g1, h, bh, bl, bd, bp1, bp2, bo, mask, out);
}